// Round 8
// baseline (370.007 us; speedup 1.0000x reference)
//
#include <hip/hip_runtime.h>
#include <hip/hip_bf16.h>

#define Nn 50000
#define Ee 600000
#define Dd 128
#define EPSc 1e-5f

typedef unsigned int u32;
typedef unsigned short u16;
typedef short s16x8 __attribute__((ext_vector_type(8)));
typedef float f32x4 __attribute__((ext_vector_type(4)));

__device__ inline float bf2f(u32 lo16) { return __uint_as_float(lo16 << 16); }
__device__ inline u16 f2bf(float f) {
    u32 b = __float_as_uint(f);
    return (u16)((b + 0x7fffu + ((b >> 16) & 1u)) >> 16);  // RTN-even
}
__device__ inline void gload16(const void* g, void* l) {
    __builtin_amdgcn_global_load_lds(
        (const __attribute__((address_space(1))) u32*)g,
        (__attribute__((address_space(3))) u32*)l, 16, 0, 0);
}

// ---------------- CSR build ----------------
__global__ __launch_bounds__(256) void hist_k(const int* __restrict__ dst,
                                              int* __restrict__ cnt) {
    int e = blockIdx.x * 256 + threadIdx.x;
    if (e < Ee) atomicAdd(&cnt[dst[e]], 1);
}

__global__ __launch_bounds__(1024) void scan_k(const int* __restrict__ cnt,
                                               int* __restrict__ rowp) {
    __shared__ int wsum[16];
    __shared__ int carry_s;
    const int t = threadIdx.x, lane = t & 63, w = t >> 6;
    if (t == 0) { carry_s = 0; rowp[0] = 0; }
    __syncthreads();
    for (int base = 0; base < Nn; base += 1024) {
        int v = (base + t < Nn) ? cnt[base + t] : 0;
        int incl = v;
#pragma unroll
        for (int off = 1; off < 64; off <<= 1) {
            int u = __shfl_up(incl, off, 64);
            if (lane >= off) incl += u;
        }
        if (lane == 63) wsum[w] = incl;
        __syncthreads();
        if (t == 0) {
            int run = carry_s;
#pragma unroll
            for (int i = 0; i < 16; i++) { int s = wsum[i]; wsum[i] = run; run += s; }
            carry_s = run;
        }
        __syncthreads();
        if (base + t < Nn) rowp[base + t + 1] = wsum[w] + incl;
        __syncthreads();
    }
}

__global__ __launch_bounds__(256) void scatter_k(const int* __restrict__ src,
                                                 const int* __restrict__ dst,
                                                 const int* __restrict__ et,
                                                 int* __restrict__ cursor,
                                                 int2* __restrict__ se) {
    int e = blockIdx.x * 256 + threadIdx.x;
    if (e < Ee) {
        int pos = atomicAdd(&cursor[dst[e]], 1);
        se[pos] = make_int2(src[e], et[e]);
    }
}

// ---------------- fp32 -> bf16 convert ----------------
__global__ __launch_bounds__(256) void conv_k(const float* __restrict__ in,
                                              u16* __restrict__ out) {
    const int total = Nn * 32;
    for (int i = blockIdx.x * 256 + threadIdx.x; i < total; i += gridDim.x * 256) {
        float4 v = ((const float4*)in)[i];
        ((ushort4*)out)[i] = make_ushort4(f2bf(v.x), f2bf(v.y), f2bf(v.z), f2bf(v.w));
    }
}

// ---------------- weight prep: Wt[c][k] = W[k][c] in bf16, k: V(512)|loop(128)
__global__ __launch_bounds__(256) void wprep_k(const float* __restrict__ V,
                                               const float* __restrict__ loop,
                                               u16* __restrict__ Wt) {
    int i = blockIdx.x * 256 + threadIdx.x;  // 128*640
    if (i >= 128 * 640) return;
    int c = i / 640, k = i - c * 640;
    float v = (k < 512) ? V[(size_t)k * 128 + c] : loop[(size_t)(k - 512) * 128 + c];
    Wt[i] = f2bf(v);
}

// ---------------- aggregation: yb16[n,b,:] = sum_e comb[et,b]*x16[src] -------
__global__ __launch_bounds__(256) void agg_k(const u16* __restrict__ x16,
                                             const int2* __restrict__ se,
                                             const int* __restrict__ rowp,
                                             const float* __restrict__ comb,
                                             u16* __restrict__ yb16) {
    const int node = blockIdx.x * 4 + (threadIdx.x >> 6);
    const int lane = threadIdx.x & 63;
    const int beg = rowp[node], end = rowp[node + 1];
    float a0x = 0.f, a0y = 0.f, a1x = 0.f, a1y = 0.f;
    float a2x = 0.f, a2y = 0.f, a3x = 0.f, a3y = 0.f;
    const int eL = end - 1;
    const int co = lane * 2;

    for (int e0 = beg; e0 < end; e0 += 4) {
        const int m = end - e0;
        const int2 rc0 = se[e0];
        const int2 rc1 = se[min(e0 + 1, eL)];
        const int2 rc2 = se[min(e0 + 2, eL)];
        const int2 rc3 = se[min(e0 + 3, eL)];
        u32 x0 = *(const u32*)&x16[(size_t)rc0.x * 128 + co];
        u32 x1 = *(const u32*)&x16[(size_t)rc1.x * 128 + co];
        u32 x2 = *(const u32*)&x16[(size_t)rc2.x * 128 + co];
        u32 x3 = *(const u32*)&x16[(size_t)rc3.x * 128 + co];
        if (m < 4) x3 = 0;
        if (m < 3) x2 = 0;
        if (m < 2) x1 = 0;
        const float4 c0 = ((const float4*)comb)[rc0.y];
        const float4 c1 = ((const float4*)comb)[rc1.y];
        const float4 c2 = ((const float4*)comb)[rc2.y];
        const float4 c3 = ((const float4*)comb)[rc3.y];
#define ACC1(c, xv)                                        \
        {                                                  \
            const float fx = bf2f((xv) & 0xffffu);         \
            const float fy = bf2f((xv) >> 16);             \
            a0x += c.x * fx; a0y += c.x * fy;              \
            a1x += c.y * fx; a1y += c.y * fy;              \
            a2x += c.z * fx; a2y += c.z * fy;              \
            a3x += c.w * fx; a3y += c.w * fy;              \
        }
        ACC1(c0, x0)
        ACC1(c1, x1)
        ACC1(c2, x2)
        ACC1(c3, x3)
#undef ACC1
    }
    u32* yp = (u32*)(yb16 + (size_t)node * 512);
    yp[lane]       = (u32)f2bf(a0x) | ((u32)f2bf(a0y) << 16);
    yp[64 + lane]  = (u32)f2bf(a1x) | ((u32)f2bf(a1y) << 16);
    yp[128 + lane] = (u32)f2bf(a2x) | ((u32)f2bf(a2y) << 16);
    yp[192 + lane] = (u32)f2bf(a3x) | ((u32)f2bf(a3y) << 16);
}

// ---------------- MFMA GEMM: OUT = relu([yb16|x16] @ Wt^T + bias) ------------
// BM=64 x BN=128, 4 waves (2x2, wave tile 32x64), BK=32.
// 4-deep LDS ring (4 x 12KB), 3-stages-ahead prefetch with COUNTED vmcnt +
// RAW s_barrier (never vmcnt(0) in steady state) -> load latency spans 3 steps.
// Fused BN stats: butterfly + LDS cross-wave reduce -> 1 atomic set per block.
__global__ __launch_bounds__(256) void gemm_mfma_k(const u16* __restrict__ yb16,
                                                   const u16* __restrict__ x16,
                                                   const u16* __restrict__ Wt,
                                                   const float* __restrict__ bias,
                                                   float* __restrict__ OUT,
                                                   float* __restrict__ stats) {
    // 4 buffers x (A 64x64B = 4KB | B 128x64B = 8KB) = 49152 B
    __shared__ __align__(16) char LDS[49152];
    const int tid = threadIdx.x;
    const int lane = tid & 63, wid = tid >> 6;
    const int wr = wid >> 1, wc = wid & 1;
    const int bm = blockIdx.x * 64;
    const int NT = 20;

    f32x4 acc[2][4] = {};

    // staging: 12 chunks of 16 rows (1024B each); rows 0-63 = A, 64-191 = B(Wt).
    // wave stages chunks [3*wid, 3*wid+3). gload_lds dest: base + lane*16 ->
    // row 16c+(lane>>2), slot lane&3. Source pre-swizzled (slot ^ (row>>1)&3).
    const u16* ybp[3];
    const u16* xp[3];
    const u16* wtp[3];
    int ldsoff[3];
#pragma unroll
    for (int j = 0; j < 3; j++) {
        const int c = wid * 3 + j;
        const int row = c * 16 + (lane >> 2);
        const int off = (((lane & 3) ^ ((row >> 1) & 3)) * 8);
        ldsoff[j] = c * 1024;
        if (row < 64) {
            int ga = bm + row;
            if (ga >= Nn) ga = Nn - 1;
            ybp[j] = yb16 + (size_t)ga * 512 + off;
            xp[j] = x16 + (size_t)ga * 128 + off;
            wtp[j] = nullptr;
        } else {
            wtp[j] = Wt + (size_t)(row - 64) * 640 + off;
            ybp[j] = nullptr;
            xp[j] = nullptr;
        }
    }

#define STAGE(buf, k0)                                                        \
    {                                                                         \
        _Pragma("unroll")                                                     \
        for (int j = 0; j < 3; j++) {                                         \
            const u16* s = wtp[j] ? (wtp[j] + (k0))                           \
                                  : ((k0) < 512 ? ybp[j] + (k0)               \
                                                : xp[j] + ((k0) - 512));      \
            gload16(s, LDS + (buf) * 12288 + ldsoff[j]);                      \
        }                                                                     \
    }

    // prologue: 3 stages in flight (9 loads/thread)
    STAGE(0, 0);
    STAGE(1, 32);
    STAGE(2, 64);

    for (int t = 0; t < NT; t++) {
        if (t + 3 < NT) STAGE((t + 3) & 3, (t + 3) * 32);
        // wait for OWN buffer-t loads (3 stages x 3 loads remain in flight)
        if (t <= NT - 4)      asm volatile("s_waitcnt vmcnt(9)" ::: "memory");
        else if (t == NT - 3) asm volatile("s_waitcnt vmcnt(6)" ::: "memory");
        else if (t == NT - 2) asm volatile("s_waitcnt vmcnt(3)" ::: "memory");
        else                  asm volatile("s_waitcnt vmcnt(0)" ::: "memory");
        __builtin_amdgcn_s_barrier();   // now all waves' buffer-t loads done

        const char* Ab = LDS + (t & 3) * 12288;
        const char* Bb = Ab + 4096;
        s16x8 a[2], b[4];
#pragma unroll
        for (int m = 0; m < 2; m++) {
            const int row = wr * 32 + m * 16 + (lane & 15);
            a[m] = *(const s16x8*)(Ab + row * 64 +
                                   (((lane >> 4) ^ ((row >> 1) & 3)) << 4));
        }
#pragma unroll
        for (int n = 0; n < 4; n++) {
            const int col = wc * 64 + n * 16 + (lane & 15);
            b[n] = *(const s16x8*)(Bb + col * 64 +
                                   (((lane >> 4) ^ ((col >> 1) & 3)) << 4));
        }
#pragma unroll
        for (int m = 0; m < 2; m++)
#pragma unroll
            for (int n = 0; n < 4; n++)
                acc[m][n] = __builtin_amdgcn_mfma_f32_16x16x32_bf16(a[m], b[n],
                                                                    acc[m][n], 0, 0, 0);
        // all LDS reads done before next iter's STAGE overwrites buf (t+4)&3==t&3... 
        // (the ring reuses buf t&3 at t+4; STAGE at t+1 writes (t+4)&3 == (t)&3? 
        //  (t+1)+3 = t+4 -> buf (t+4)&3 == t&3 -> must not overwrite until reads done)
        asm volatile("s_waitcnt lgkmcnt(0)" ::: "memory");
        __builtin_amdgcn_s_barrier();
    }
#undef STAGE

    // epilogue: D frag col=lane&15, row=(lane>>4)*4+e. Fused BN stats.
    float bv[4], cs[4] = {}, cq[4] = {};
#pragma unroll
    for (int n = 0; n < 4; n++) bv[n] = bias[wc * 64 + n * 16 + (lane & 15)];
#pragma unroll
    for (int m = 0; m < 2; m++) {
        const int rb = bm + wr * 32 + m * 16 + ((lane >> 4) << 2);
#pragma unroll
        for (int e = 0; e < 4; e++) {
            const int r = rb + e;
            if (r < Nn) {
                float* op = OUT + (size_t)r * 128 + wc * 64 + (lane & 15);
#pragma unroll
                for (int n = 0; n < 4; n++) {
                    float v = fmaxf(acc[m][n][e] + bv[n], 0.f);
                    op[n * 16] = v;
                    cs[n] += v;
                    cq[n] += v * v;
                }
            }
        }
    }
#pragma unroll
    for (int n = 0; n < 4; n++) {
        cs[n] += __shfl_xor(cs[n], 16);
        cs[n] += __shfl_xor(cs[n], 32);
        cq[n] += __shfl_xor(cq[n], 16);
        cq[n] += __shfl_xor(cq[n], 32);
    }
    // cross-wave (wr) pre-reduce in LDS -> one atomic set per block
    float* red = (float*)LDS;
    if (wr == 1 && lane < 16) {
#pragma unroll
        for (int n = 0; n < 4; n++) {
            const int col = wc * 64 + n * 16 + lane;
            red[col] = cs[n];
            red[128 + col] = cq[n];
        }
    }
    __syncthreads();
    if (wr == 0 && lane < 16) {
#pragma unroll
        for (int n = 0; n < 4; n++) {
            const int col = wc * 64 + n * 16 + lane;
            unsafeAtomicAdd(&stats[col], cs[n] + red[col]);
            unsafeAtomicAdd(&stats[128 + col], cq[n] + red[128 + col]);
        }
    }
}

// ---------------- BN normalize (+ optional bf16 emit for next layer) ---------
__global__ __launch_bounds__(256) void norm_k(const float* __restrict__ h,
                                              const float* __restrict__ stats,
                                              const float* __restrict__ gamma,
                                              const float* __restrict__ beta,
                                              float* __restrict__ out,
                                              u16* __restrict__ xb) {
    const float invN = 1.0f / (float)Nn;
    int total = Nn * 32;
    for (int i = blockIdx.x * blockDim.x + threadIdx.x; i < total;
         i += gridDim.x * blockDim.x) {
        int c = (i & 31) * 4;
        float4 v = ((const float4*)h)[i];
        float4 o;
        {
            float mu = stats[c + 0] * invN;
            float var = stats[Dd + c + 0] * invN - mu * mu;
            o.x = gamma[c + 0] * (v.x - mu) * rsqrtf(var + EPSc) + beta[c + 0];
        }
        {
            float mu = stats[c + 1] * invN;
            float var = stats[Dd + c + 1] * invN - mu * mu;
            o.y = gamma[c + 1] * (v.y - mu) * rsqrtf(var + EPSc) + beta[c + 1];
        }
        {
            float mu = stats[c + 2] * invN;
            float var = stats[Dd + c + 2] * invN - mu * mu;
            o.z = gamma[c + 2] * (v.z - mu) * rsqrtf(var + EPSc) + beta[c + 2];
        }
        {
            float mu = stats[c + 3] * invN;
            float var = stats[Dd + c + 3] * invN - mu * mu;
            o.w = gamma[c + 3] * (v.w - mu) * rsqrtf(var + EPSc) + beta[c + 3];
        }
        ((float4*)out)[i] = o;
        if (xb) ((ushort4*)xb)[i] = make_ushort4(f2bf(o.x), f2bf(o.y),
                                                 f2bf(o.z), f2bf(o.w));
    }
}

// ---------------- launch ----------------
extern "C" void kernel_launch(void* const* d_in, const int* in_sizes, int n_in,
                              void* d_out, int out_size, void* d_ws, size_t ws_size,
                              hipStream_t stream) {
    const float* feat = (const float*)d_in[0];
    const int* src = (const int*)d_in[1];
    const int* dst = (const int*)d_in[2];
    const int* et = (const int*)d_in[3];
    float* out = (float*)d_out;

    // workspace (~69.2 MB)
    char* p = (char*)d_ws;
    u16* yb16 = (u16*)p;   p += (size_t)Nn * 512 * 2;                    // 51.2 MB
    u16* x16 = (u16*)p;    p += (size_t)Nn * 128 * 2;                    // 12.8 MB
    u16* Wt = (u16*)p;     p += (size_t)128 * 640 * 2;                   // 160 KB
    int* rowp = (int*)p;   p += ((((size_t)(Nn + 1) * 4) + 15) & ~15ull);
    int2* se = (int2*)p;   p += (size_t)Ee * 8;                          // 4.8 MB
    float* stats = (float*)p;
    int* cursor = (int*)yb16;  // dead before agg_k writes yb16

    // ---- CSR once ----
    hipMemsetAsync(cursor, 0, (size_t)Nn * 4, stream);
    hist_k<<<(Ee + 255) / 256, 256, 0, stream>>>(dst, cursor);
    scan_k<<<1, 1024, 0, stream>>>(cursor, rowp);
    hipMemcpyAsync(cursor, rowp, (size_t)Nn * 4, hipMemcpyDeviceToDevice, stream);
    scatter_k<<<(Ee + 255) / 256, 256, 0, stream>>>(src, dst, et, cursor, se);
    conv_k<<<1024, 256, 0, stream>>>(feat, x16);

    const int gx = (Nn + 63) / 64;  // 782

    for (int l = 0; l < 2; l++) {
        const float* V = (const float*)d_in[4 + 6 * l + 0];
        const float* comb = (const float*)d_in[4 + 6 * l + 1];
        const float* loop = (const float*)d_in[4 + 6 * l + 2];
        const float* bias = (const float*)d_in[4 + 6 * l + 3];
        const float* gamma = (const float*)d_in[4 + 6 * l + 4];
        const float* beta = (const float*)d_in[4 + 6 * l + 5];

        wprep_k<<<(128 * 640 + 255) / 256, 256, 0, stream>>>(V, loop, Wt);
        agg_k<<<(Nn + 3) / 4, 256, 0, stream>>>(x16, se, rowp, comb, yb16);
        hipMemsetAsync(stats, 0, 2 * Dd * sizeof(float), stream);
        gemm_mfma_k<<<gx, 256, 0, stream>>>(yb16, x16, Wt, bias, out, stats);
        norm_k<<<2048, 256, 0, stream>>>(out, stats, gamma, beta, out,
                                         (l == 0) ? x16 : nullptr);
    }
}

// Round 9
// 317.430 us; speedup vs baseline: 1.1656x; 1.1656x over previous
//
#include <hip/hip_runtime.h>
#include <hip/hip_bf16.h>

#define Nn 50000
#define Ee 600000
#define Dd 128
#define EPSc 1e-5f
#define GX 391  // gemm grid: ceil(50000/128)

typedef unsigned int u32;
typedef unsigned short u16;
typedef short s16x8 __attribute__((ext_vector_type(8)));
typedef float f32x4 __attribute__((ext_vector_type(4)));

__device__ inline float bf2f(u32 lo16) { return __uint_as_float(lo16 << 16); }
__device__ inline u16 f2bf(float f) {
    u32 b = __float_as_uint(f);
    return (u16)((b + 0x7fffu + ((b >> 16) & 1u)) >> 16);  // RTN-even
}
__device__ inline void gload16(const void* g, void* l) {
    __builtin_amdgcn_global_load_lds(
        (const __attribute__((address_space(1))) u32*)g,
        (__attribute__((address_space(3))) u32*)l, 16, 0, 0);
}

// ---------------- CSR build ----------------
__global__ __launch_bounds__(256) void hist_k(const int* __restrict__ dst,
                                              int* __restrict__ cnt) {
    int e = blockIdx.x * 256 + threadIdx.x;
    if (e < Ee) atomicAdd(&cnt[dst[e]], 1);
}

__global__ __launch_bounds__(1024) void scan_k(const int* __restrict__ cnt,
                                               int* __restrict__ rowp) {
    __shared__ int wsum[16];
    __shared__ int carry_s;
    const int t = threadIdx.x, lane = t & 63, w = t >> 6;
    if (t == 0) { carry_s = 0; rowp[0] = 0; }
    __syncthreads();
    for (int base = 0; base < Nn; base += 1024) {
        int v = (base + t < Nn) ? cnt[base + t] : 0;
        int incl = v;
#pragma unroll
        for (int off = 1; off < 64; off <<= 1) {
            int u = __shfl_up(incl, off, 64);
            if (lane >= off) incl += u;
        }
        if (lane == 63) wsum[w] = incl;
        __syncthreads();
        if (t == 0) {
            int run = carry_s;
#pragma unroll
            for (int i = 0; i < 16; i++) { int s = wsum[i]; wsum[i] = run; run += s; }
            carry_s = run;
        }
        __syncthreads();
        if (base + t < Nn) rowp[base + t + 1] = wsum[w] + incl;
        __syncthreads();
    }
}

__global__ __launch_bounds__(256) void scatter_k(const int* __restrict__ src,
                                                 const int* __restrict__ dst,
                                                 const int* __restrict__ et,
                                                 int* __restrict__ cursor,
                                                 int2* __restrict__ se) {
    int e = blockIdx.x * 256 + threadIdx.x;
    if (e < Ee) {
        int pos = atomicAdd(&cursor[dst[e]], 1);
        se[pos] = make_int2(src[e], et[e]);
    }
}

// ---------------- fp32 -> bf16 convert ----------------
__global__ __launch_bounds__(256) void conv_k(const float* __restrict__ in,
                                              u16* __restrict__ out) {
    const int total = Nn * 32;
    for (int i = blockIdx.x * 256 + threadIdx.x; i < total; i += gridDim.x * 256) {
        float4 v = ((const float4*)in)[i];
        ((ushort4*)out)[i] = make_ushort4(f2bf(v.x), f2bf(v.y), f2bf(v.z), f2bf(v.w));
    }
}

// ---------------- weight prep: Wt[c][k] = W[k][c] in bf16, k: V(512)|loop(128)
__global__ __launch_bounds__(256) void wprep_k(const float* __restrict__ V,
                                               const float* __restrict__ loop,
                                               u16* __restrict__ Wt) {
    int i = blockIdx.x * 256 + threadIdx.x;  // 128*640
    if (i >= 128 * 640) return;
    int c = i / 640, k = i - c * 640;
    float v = (k < 512) ? V[(size_t)k * 128 + c] : loop[(size_t)(k - 512) * 128 + c];
    Wt[i] = f2bf(v);
}

// ---------------- aggregation: yb16[n,b,:] = sum_e comb[et,b]*x16[src] -------
__global__ __launch_bounds__(256) void agg_k(const u16* __restrict__ x16,
                                             const int2* __restrict__ se,
                                             const int* __restrict__ rowp,
                                             const float* __restrict__ comb,
                                             u16* __restrict__ yb16) {
    const int node = blockIdx.x * 4 + (threadIdx.x >> 6);
    const int lane = threadIdx.x & 63;
    const int beg = rowp[node], end = rowp[node + 1];
    float a0x = 0.f, a0y = 0.f, a1x = 0.f, a1y = 0.f;
    float a2x = 0.f, a2y = 0.f, a3x = 0.f, a3y = 0.f;
    const int eL = end - 1;
    const int co = lane * 2;

    for (int e0 = beg; e0 < end; e0 += 4) {
        const int m = end - e0;
        const int2 rc0 = se[e0];
        const int2 rc1 = se[min(e0 + 1, eL)];
        const int2 rc2 = se[min(e0 + 2, eL)];
        const int2 rc3 = se[min(e0 + 3, eL)];
        u32 x0 = *(const u32*)&x16[(size_t)rc0.x * 128 + co];
        u32 x1 = *(const u32*)&x16[(size_t)rc1.x * 128 + co];
        u32 x2 = *(const u32*)&x16[(size_t)rc2.x * 128 + co];
        u32 x3 = *(const u32*)&x16[(size_t)rc3.x * 128 + co];
        if (m < 4) x3 = 0;
        if (m < 3) x2 = 0;
        if (m < 2) x1 = 0;
        const float4 c0 = ((const float4*)comb)[rc0.y];
        const float4 c1 = ((const float4*)comb)[rc1.y];
        const float4 c2 = ((const float4*)comb)[rc2.y];
        const float4 c3 = ((const float4*)comb)[rc3.y];
#define ACC1(c, xv)                                        \
        {                                                  \
            const float fx = bf2f((xv) & 0xffffu);         \
            const float fy = bf2f((xv) >> 16);             \
            a0x += c.x * fx; a0y += c.x * fy;              \
            a1x += c.y * fx; a1y += c.y * fy;              \
            a2x += c.z * fx; a2y += c.z * fy;              \
            a3x += c.w * fx; a3y += c.w * fy;              \
        }
        ACC1(c0, x0)
        ACC1(c1, x1)
        ACC1(c2, x2)
        ACC1(c3, x3)
#undef ACC1
    }
    u32* yp = (u32*)(yb16 + (size_t)node * 512);
    yp[lane]       = (u32)f2bf(a0x) | ((u32)f2bf(a0y) << 16);
    yp[64 + lane]  = (u32)f2bf(a1x) | ((u32)f2bf(a1y) << 16);
    yp[128 + lane] = (u32)f2bf(a2x) | ((u32)f2bf(a2y) << 16);
    yp[192 + lane] = (u32)f2bf(a3x) | ((u32)f2bf(a3y) << 16);
}

// ---------------- MFMA GEMM: OUT = relu([yb16|x16] @ Wt^T + bias) ------------
// R4-proven structure: BM=128,BN=128,BK=32, 4 waves (2x2 of 64x64), single
// 16KB LDS buffer, plain __syncthreads. Epilogue: per-block column partials
// (sum|sumsq) -> plain stores to partials[bid][256]; NO atomics.
__global__ __launch_bounds__(256) void gemm_mfma_k(const u16* __restrict__ yb16,
                                                   const u16* __restrict__ x16,
                                                   const u16* __restrict__ Wt,
                                                   const float* __restrict__ bias,
                                                   float* __restrict__ OUT,
                                                   float* __restrict__ partials) {
    __shared__ __align__(16) char As[8192];  // 128 rows x 64 B
    __shared__ __align__(16) char Bs[8192];  // 128 cols x 64 B
    const int tid = threadIdx.x;
    const int lane = tid & 63, wid = tid >> 6;
    const int wr = wid >> 1, wc = wid & 1;
    const int bm = blockIdx.x * 128;

    f32x4 acc[4][4] = {};

    // staging geometry: wave stages LDS rows [wid*32, wid*32+32) of As and Bs
    const int r0 = wid * 32;
    const int lrow = lane >> 2;       // 0..15
    const int sphys = lane & 3;       // 16B slot within 64B row
    const int rowL0 = r0 + lrow, rowL1 = r0 + 16 + lrow;
    const int slog0 = (sphys ^ ((rowL0 >> 1) & 3)) * 8;  // element offset
    const int slog1 = (sphys ^ ((rowL1 >> 1) & 3)) * 8;
    int ga0 = bm + rowL0; if (ga0 >= Nn) ga0 = Nn - 1;
    int ga1 = bm + rowL1; if (ga1 >= Nn) ga1 = Nn - 1;

    for (int k0 = 0; k0 < 640; k0 += 32) {
        __syncthreads();
        const u16 *as0, *as1;
        if (k0 < 512) {
            as0 = yb16 + (size_t)ga0 * 512 + k0 + slog0;
            as1 = yb16 + (size_t)ga1 * 512 + k0 + slog1;
        } else {
            as0 = x16 + (size_t)ga0 * 128 + (k0 - 512) + slog0;
            as1 = x16 + (size_t)ga1 * 128 + (k0 - 512) + slog1;
        }
        gload16(as0, &As[r0 * 64]);
        gload16(as1, &As[(r0 + 16) * 64]);
        gload16(Wt + (size_t)rowL0 * 640 + k0 + slog0, &Bs[r0 * 64]);
        gload16(Wt + (size_t)rowL1 * 640 + k0 + slog1, &Bs[(r0 + 16) * 64]);
        __syncthreads();
        s16x8 a[4], b[4];
#pragma unroll
        for (int m = 0; m < 4; m++) {
            int row = wr * 64 + m * 16 + (lane & 15);
            a[m] = *(const s16x8*)&As[row * 64 + (((lane >> 4) ^ ((row >> 1) & 3)) << 4)];
            int col = wc * 64 + m * 16 + (lane & 15);
            b[m] = *(const s16x8*)&Bs[col * 64 + (((lane >> 4) ^ ((col >> 1) & 3)) << 4)];
        }
#pragma unroll
        for (int m = 0; m < 4; m++)
#pragma unroll
            for (int n = 0; n < 4; n++)
                acc[m][n] = __builtin_amdgcn_mfma_f32_16x16x32_bf16(a[m], b[n],
                                                                    acc[m][n], 0, 0, 0);
    }
    // epilogue: D frag col=lane&15, row=(lane>>4)*4+e. Column partials, no atomics.
    float bv[4], cs[4] = {}, cq[4] = {};
#pragma unroll
    for (int n = 0; n < 4; n++) bv[n] = bias[wc * 64 + n * 16 + (lane & 15)];
#pragma unroll
    for (int m = 0; m < 4; m++) {
        const int rb = bm + wr * 64 + m * 16 + ((lane >> 4) << 2);
#pragma unroll
        for (int e = 0; e < 4; e++) {
            const int r = rb + e;
            if (r < Nn) {
                float* op = OUT + (size_t)r * 128 + wc * 64 + (lane & 15);
#pragma unroll
                for (int n = 0; n < 4; n++) {
                    float v = fmaxf(acc[m][n][e] + bv[n], 0.f);
                    op[n * 16] = v;
                    cs[n] += v;
                    cq[n] += v * v;
                }
            }
        }
    }
#pragma unroll
    for (int n = 0; n < 4; n++) {
        cs[n] += __shfl_xor(cs[n], 16);
        cs[n] += __shfl_xor(cs[n], 32);
        cq[n] += __shfl_xor(cq[n], 16);
        cq[n] += __shfl_xor(cq[n], 32);
    }
    __syncthreads();   // all LDS reads of K-loop done before reuse
    float* red = (float*)As;
    if (wr == 1 && lane < 16) {
#pragma unroll
        for (int n = 0; n < 4; n++) {
            const int col = wc * 64 + n * 16 + lane;
            red[col] = cs[n];
            red[128 + col] = cq[n];
        }
    }
    __syncthreads();
    if (wr == 0 && lane < 16) {
        float* pp = partials + (size_t)blockIdx.x * 256;
#pragma unroll
        for (int n = 0; n < 4; n++) {
            const int col = wc * 64 + n * 16 + lane;
            pp[col] = cs[n] + red[col];
            pp[128 + col] = cq[n] + red[128 + col];
        }
    }
}

// ---------------- partials reduce: stats[c] = sum_b partials[b][c] ----------
__global__ __launch_bounds__(256) void red_k(const float* __restrict__ partials,
                                             float* __restrict__ stats) {
    const int c = threadIdx.x;
    float s = 0.f;
    for (int b = blockIdx.x; b < GX; b += gridDim.x)
        s += partials[(size_t)b * 256 + c];
    unsafeAtomicAdd(&stats[c], s);   // gridDim.x adds per address
}

// ---------------- BN normalize (+ optional bf16 emit for next layer) ---------
__global__ __launch_bounds__(256) void norm_k(const float* __restrict__ h,
                                              const float* __restrict__ stats,
                                              const float* __restrict__ gamma,
                                              const float* __restrict__ beta,
                                              float* __restrict__ out,
                                              u16* __restrict__ xb) {
    const float invN = 1.0f / (float)Nn;
    int total = Nn * 32;
    for (int i = blockIdx.x * blockDim.x + threadIdx.x; i < total;
         i += gridDim.x * blockDim.x) {
        int c = (i & 31) * 4;
        float4 v = ((const float4*)h)[i];
        float4 o;
        {
            float mu = stats[c + 0] * invN;
            float var = stats[Dd + c + 0] * invN - mu * mu;
            o.x = gamma[c + 0] * (v.x - mu) * rsqrtf(var + EPSc) + beta[c + 0];
        }
        {
            float mu = stats[c + 1] * invN;
            float var = stats[Dd + c + 1] * invN - mu * mu;
            o.y = gamma[c + 1] * (v.y - mu) * rsqrtf(var + EPSc) + beta[c + 1];
        }
        {
            float mu = stats[c + 2] * invN;
            float var = stats[Dd + c + 2] * invN - mu * mu;
            o.z = gamma[c + 2] * (v.z - mu) * rsqrtf(var + EPSc) + beta[c + 2];
        }
        {
            float mu = stats[c + 3] * invN;
            float var = stats[Dd + c + 3] * invN - mu * mu;
            o.w = gamma[c + 3] * (v.w - mu) * rsqrtf(var + EPSc) + beta[c + 3];
        }
        ((float4*)out)[i] = o;
        if (xb) ((ushort4*)xb)[i] = make_ushort4(f2bf(o.x), f2bf(o.y),
                                                 f2bf(o.z), f2bf(o.w));
    }
}

// ---------------- launch ----------------
extern "C" void kernel_launch(void* const* d_in, const int* in_sizes, int n_in,
                              void* d_out, int out_size, void* d_ws, size_t ws_size,
                              hipStream_t stream) {
    const float* feat = (const float*)d_in[0];
    const int* src = (const int*)d_in[1];
    const int* dst = (const int*)d_in[2];
    const int* et = (const int*)d_in[3];
    float* out = (float*)d_out;

    // workspace (~69.7 MB)
    char* p = (char*)d_ws;
    u16* yb16 = (u16*)p;     p += (size_t)Nn * 512 * 2;                  // 51.2 MB
    u16* x16 = (u16*)p;      p += (size_t)Nn * 128 * 2;                  // 12.8 MB
    u16* Wt = (u16*)p;       p += (size_t)128 * 640 * 2;                 // 160 KB
    int* rowp = (int*)p;     p += ((((size_t)(Nn + 1) * 4) + 15) & ~15ull);
    int2* se = (int2*)p;     p += (size_t)Ee * 8;                        // 4.8 MB
    float* partials = (float*)p;  p += (size_t)GX * 256 * 4;             // 400 KB
    float* stats = (float*)p;
    int* cursor = (int*)yb16;  // dead before agg_k writes yb16

    // ---- CSR once ----
    hipMemsetAsync(cursor, 0, (size_t)Nn * 4, stream);
    hist_k<<<(Ee + 255) / 256, 256, 0, stream>>>(dst, cursor);
    scan_k<<<1, 1024, 0, stream>>>(cursor, rowp);
    hipMemcpyAsync(cursor, rowp, (size_t)Nn * 4, hipMemcpyDeviceToDevice, stream);
    scatter_k<<<(Ee + 255) / 256, 256, 0, stream>>>(src, dst, et, cursor, se);
    conv_k<<<1024, 256, 0, stream>>>(feat, x16);

    for (int l = 0; l < 2; l++) {
        const float* V = (const float*)d_in[4 + 6 * l + 0];
        const float* comb = (const float*)d_in[4 + 6 * l + 1];
        const float* loop = (const float*)d_in[4 + 6 * l + 2];
        const float* bias = (const float*)d_in[4 + 6 * l + 3];
        const float* gamma = (const float*)d_in[4 + 6 * l + 4];
        const float* beta = (const float*)d_in[4 + 6 * l + 5];

        wprep_k<<<(128 * 640 + 255) / 256, 256, 0, stream>>>(V, loop, Wt);
        agg_k<<<(Nn + 3) / 4, 256, 0, stream>>>(x16, se, rowp, comb, yb16);
        hipMemsetAsync(stats, 0, 2 * Dd * sizeof(float), stream);
        gemm_mfma_k<<<GX, 256, 0, stream>>>(yb16, x16, Wt, bias, out, partials);
        red_k<<<8, 256, 0, stream>>>(partials, stats);
        norm_k<<<2048, 256, 0, stream>>>(out, stats, gamma, beta, out,
                                         (l == 0) ? x16 : nullptr);
    }
}

// Round 10
// 292.830 us; speedup vs baseline: 1.2636x; 1.0840x over previous
//
#include <hip/hip_runtime.h>
#include <hip/hip_bf16.h>

#define Nn 50000
#define Ee 600000
#define Dd 128
#define EPSc 1e-5f
#define GX 391   // gemm grid: ceil(50000/128)
#define NB 196   // scan tiles: ceil(50000/256)

typedef unsigned int u32;
typedef unsigned short u16;
typedef short s16x8 __attribute__((ext_vector_type(8)));
typedef float f32x4 __attribute__((ext_vector_type(4)));

__device__ inline float bf2f(u32 lo16) { return __uint_as_float(lo16 << 16); }
__device__ inline u16 f2bf(float f) {
    u32 b = __float_as_uint(f);
    return (u16)((b + 0x7fffu + ((b >> 16) & 1u)) >> 16);  // RTN-even
}
__device__ inline void gload16(const void* g, void* l) {
    __builtin_amdgcn_global_load_lds(
        (const __attribute__((address_space(1))) u32*)g,
        (__attribute__((address_space(3))) u32*)l, 16, 0, 0);
}

// ---------------- CSR build: histogram ----------------
__global__ __launch_bounds__(256) void hist_k(const int* __restrict__ dst,
                                              int* __restrict__ cnt) {
    int e = blockIdx.x * 256 + threadIdx.x;
    if (e < Ee) atomicAdd(&cnt[dst[e]], 1);
}

// ---------------- 3-pass scan ----------------
__global__ __launch_bounds__(256) void scanA_k(const int* __restrict__ cnt,
                                               int* __restrict__ rowp,
                                               int* __restrict__ bsum) {
    __shared__ int ws4[4];
    const int tid = threadIdx.x, lane = tid & 63, w = tid >> 6;
    const int i = blockIdx.x * 256 + tid;
    int v = (i < Nn) ? cnt[i] : 0;
    int incl = v;
#pragma unroll
    for (int off = 1; off < 64; off <<= 1) {
        int u = __shfl_up(incl, off, 64);
        if (lane >= off) incl += u;
    }
    if (lane == 63) ws4[w] = incl;
    __syncthreads();
    if (tid == 0) {
        int run = 0;
#pragma unroll
        for (int j = 0; j < 4; j++) { int s = ws4[j]; ws4[j] = run; run += s; }
    }
    __syncthreads();
    incl += ws4[w];
    if (i < Nn) rowp[i + 1] = incl;
    if (tid == 255) bsum[blockIdx.x] = incl;
}

__global__ __launch_bounds__(256) void scanB_k(const int* __restrict__ bsum,
                                               int* __restrict__ boff) {
    __shared__ int ws4[4];
    const int tid = threadIdx.x, lane = tid & 63, w = tid >> 6;
    int v = (tid < NB) ? bsum[tid] : 0;
    int incl = v;
#pragma unroll
    for (int off = 1; off < 64; off <<= 1) {
        int u = __shfl_up(incl, off, 64);
        if (lane >= off) incl += u;
    }
    if (lane == 63) ws4[w] = incl;
    __syncthreads();
    if (tid == 0) {
        int run = 0;
#pragma unroll
        for (int j = 0; j < 4; j++) { int s = ws4[j]; ws4[j] = run; run += s; }
    }
    __syncthreads();
    if (tid < NB) boff[tid] = incl + ws4[w] - v;  // exclusive
}

__global__ __launch_bounds__(256) void scanC_k(const int* __restrict__ boff,
                                               int* __restrict__ rowp) {
    const int i = blockIdx.x * 256 + threadIdx.x;
    if (i < Nn) rowp[i + 1] += boff[blockIdx.x];
    if (i == 0) rowp[0] = 0;
}

__global__ __launch_bounds__(256) void scatter_k(const int* __restrict__ src,
                                                 const int* __restrict__ dst,
                                                 const int* __restrict__ et,
                                                 int* __restrict__ cursor,
                                                 int2* __restrict__ se) {
    int e = blockIdx.x * 256 + threadIdx.x;
    if (e < Ee) {
        int pos = atomicAdd(&cursor[dst[e]], 1);
        se[pos] = make_int2(src[e], et[e]);
    }
}

// ---------------- fp32 -> bf16 convert ----------------
__global__ __launch_bounds__(256) void conv_k(const float* __restrict__ in,
                                              u16* __restrict__ out) {
    const int total = Nn * 32;
    for (int i = blockIdx.x * 256 + threadIdx.x; i < total; i += gridDim.x * 256) {
        float4 v = ((const float4*)in)[i];
        ((ushort4*)out)[i] = make_ushort4(f2bf(v.x), f2bf(v.y), f2bf(v.z), f2bf(v.w));
    }
}

// ---------------- weight prep: Wt[c][k] = W[k][c] in bf16, k: V(512)|loop(128)
__global__ __launch_bounds__(256) void wprep_k(const float* __restrict__ V,
                                               const float* __restrict__ loop,
                                               u16* __restrict__ Wt) {
    int i = blockIdx.x * 256 + threadIdx.x;  // 128*640
    if (i >= 128 * 640) return;
    int c = i / 640, k = i - c * 640;
    float v = (k < 512) ? V[(size_t)k * 128 + c] : loop[(size_t)(k - 512) * 128 + c];
    Wt[i] = f2bf(v);
}

// ---------------- aggregation: yb16[n,b,:] = sum_e comb[et,b]*x16[src] -------
// 8-deep MLP: 8 clamped se loads -> 8 independent x-row gathers in flight per
// wave; tail edges zero-masked on the gathered value. u32 gather offsets.
__global__ __launch_bounds__(256) void agg_k(const u16* __restrict__ x16,
                                             const int2* __restrict__ se,
                                             const int* __restrict__ rowp,
                                             const float* __restrict__ comb,
                                             u16* __restrict__ yb16) {
    const int node = blockIdx.x * 4 + (threadIdx.x >> 6);
    const int lane = threadIdx.x & 63;
    const int beg = rowp[node], end = rowp[node + 1];
    float a0x = 0.f, a0y = 0.f, a1x = 0.f, a1y = 0.f;
    float a2x = 0.f, a2y = 0.f, a3x = 0.f, a3y = 0.f;
    const int eL = end - 1;
    const u32 co = (u32)lane * 2u;

    for (int e0 = beg; e0 < end; e0 += 8) {
        const int m = end - e0;
        int2 rc[8];
        u32 xv[8];
#pragma unroll
        for (int j = 0; j < 8; j++) rc[j] = se[min(e0 + j, eL)];
#pragma unroll
        for (int j = 0; j < 8; j++)
            xv[j] = *(const u32*)&x16[(u32)rc[j].x * 128u + co];
#pragma unroll
        for (int j = 1; j < 8; j++)
            if (m <= j) xv[j] = 0;
#pragma unroll
        for (int j = 0; j < 8; j++) {
            const float4 c = ((const float4*)comb)[rc[j].y];
            const float fx = bf2f(xv[j] & 0xffffu);
            const float fy = bf2f(xv[j] >> 16);
            a0x += c.x * fx; a0y += c.x * fy;
            a1x += c.y * fx; a1y += c.y * fy;
            a2x += c.z * fx; a2y += c.z * fy;
            a3x += c.w * fx; a3y += c.w * fy;
        }
    }
    u32* yp = (u32*)(yb16 + (size_t)node * 512);
    yp[lane]       = (u32)f2bf(a0x) | ((u32)f2bf(a0y) << 16);
    yp[64 + lane]  = (u32)f2bf(a1x) | ((u32)f2bf(a1y) << 16);
    yp[128 + lane] = (u32)f2bf(a2x) | ((u32)f2bf(a2y) << 16);
    yp[192 + lane] = (u32)f2bf(a3x) | ((u32)f2bf(a3y) << 16);
}

// ---------------- MFMA GEMM: OUT = relu([yb16|x16] @ Wt^T + bias) ------------
// BM=128,BN=128,BK=32, 4 waves (2x2 of 64x64), single 16KB LDS buffer.
// Epilogue: per-block column partials (sum|sumsq) -> plain stores, NO atomics.
__global__ __launch_bounds__(256) void gemm_mfma_k(const u16* __restrict__ yb16,
                                                   const u16* __restrict__ x16,
                                                   const u16* __restrict__ Wt,
                                                   const float* __restrict__ bias,
                                                   float* __restrict__ OUT,
                                                   float* __restrict__ partials) {
    __shared__ __align__(16) char As[8192];  // 128 rows x 64 B
    __shared__ __align__(16) char Bs[8192];  // 128 cols x 64 B
    const int tid = threadIdx.x;
    const int lane = tid & 63, wid = tid >> 6;
    const int wr = wid >> 1, wc = wid & 1;
    const int bm = blockIdx.x * 128;

    f32x4 acc[4][4] = {};

    const int r0 = wid * 32;
    const int lrow = lane >> 2;
    const int sphys = lane & 3;
    const int rowL0 = r0 + lrow, rowL1 = r0 + 16 + lrow;
    const int slog0 = (sphys ^ ((rowL0 >> 1) & 3)) * 8;
    const int slog1 = (sphys ^ ((rowL1 >> 1) & 3)) * 8;
    int ga0 = bm + rowL0; if (ga0 >= Nn) ga0 = Nn - 1;
    int ga1 = bm + rowL1; if (ga1 >= Nn) ga1 = Nn - 1;

    for (int k0 = 0; k0 < 640; k0 += 32) {
        __syncthreads();
        const u16 *as0, *as1;
        if (k0 < 512) {
            as0 = yb16 + (size_t)ga0 * 512 + k0 + slog0;
            as1 = yb16 + (size_t)ga1 * 512 + k0 + slog1;
        } else {
            as0 = x16 + (size_t)ga0 * 128 + (k0 - 512) + slog0;
            as1 = x16 + (size_t)ga1 * 128 + (k0 - 512) + slog1;
        }
        gload16(as0, &As[r0 * 64]);
        gload16(as1, &As[(r0 + 16) * 64]);
        gload16(Wt + (size_t)rowL0 * 640 + k0 + slog0, &Bs[r0 * 64]);
        gload16(Wt + (size_t)rowL1 * 640 + k0 + slog1, &Bs[(r0 + 16) * 64]);
        __syncthreads();
        s16x8 a[4], b[4];
#pragma unroll
        for (int m = 0; m < 4; m++) {
            int row = wr * 64 + m * 16 + (lane & 15);
            a[m] = *(const s16x8*)&As[row * 64 + (((lane >> 4) ^ ((row >> 1) & 3)) << 4)];
            int col = wc * 64 + m * 16 + (lane & 15);
            b[m] = *(const s16x8*)&Bs[col * 64 + (((lane >> 4) ^ ((col >> 1) & 3)) << 4)];
        }
#pragma unroll
        for (int m = 0; m < 4; m++)
#pragma unroll
            for (int n = 0; n < 4; n++)
                acc[m][n] = __builtin_amdgcn_mfma_f32_16x16x32_bf16(a[m], b[n],
                                                                    acc[m][n], 0, 0, 0);
    }
    float bv[4], cs[4] = {}, cq[4] = {};
#pragma unroll
    for (int n = 0; n < 4; n++) bv[n] = bias[wc * 64 + n * 16 + (lane & 15)];
#pragma unroll
    for (int m = 0; m < 4; m++) {
        const int rb = bm + wr * 64 + m * 16 + ((lane >> 4) << 2);
#pragma unroll
        for (int e = 0; e < 4; e++) {
            const int r = rb + e;
            if (r < Nn) {
                float* op = OUT + (size_t)r * 128 + wc * 64 + (lane & 15);
#pragma unroll
                for (int n = 0; n < 4; n++) {
                    float v = fmaxf(acc[m][n][e] + bv[n], 0.f);
                    op[n * 16] = v;
                    cs[n] += v;
                    cq[n] += v * v;
                }
            }
        }
    }
#pragma unroll
    for (int n = 0; n < 4; n++) {
        cs[n] += __shfl_xor(cs[n], 16);
        cs[n] += __shfl_xor(cs[n], 32);
        cq[n] += __shfl_xor(cq[n], 16);
        cq[n] += __shfl_xor(cq[n], 32);
    }
    __syncthreads();
    float* red = (float*)As;
    if (wr == 1 && lane < 16) {
#pragma unroll
        for (int n = 0; n < 4; n++) {
            const int col = wc * 64 + n * 16 + lane;
            red[col] = cs[n];
            red[128 + col] = cq[n];
        }
    }
    __syncthreads();
    if (wr == 0 && lane < 16) {
        float* pp = partials + (size_t)blockIdx.x * 256;
#pragma unroll
        for (int n = 0; n < 4; n++) {
            const int col = wc * 64 + n * 16 + lane;
            pp[col] = cs[n] + red[col];
            pp[128 + col] = cq[n] + red[128 + col];
        }
    }
}

// ---------------- partials reduce ----------------
__global__ __launch_bounds__(256) void red_k(const float* __restrict__ partials,
                                             float* __restrict__ stats) {
    const int c = threadIdx.x;
    float s = 0.f;
    for (int b = blockIdx.x; b < GX; b += gridDim.x)
        s += partials[(size_t)b * 256 + c];
    unsafeAtomicAdd(&stats[c], s);
}

// ---------------- BN normalize (+ optional bf16 emit for next layer) ---------
__global__ __launch_bounds__(256) void norm_k(const float* __restrict__ h,
                                              const float* __restrict__ stats,
                                              const float* __restrict__ gamma,
                                              const float* __restrict__ beta,
                                              float* __restrict__ out,
                                              u16* __restrict__ xb) {
    const float invN = 1.0f / (float)Nn;
    int total = Nn * 32;
    for (int i = blockIdx.x * blockDim.x + threadIdx.x; i < total;
         i += gridDim.x * blockDim.x) {
        int c = (i & 31) * 4;
        float4 v = ((const float4*)h)[i];
        float4 o;
        {
            float mu = stats[c + 0] * invN;
            float var = stats[Dd + c + 0] * invN - mu * mu;
            o.x = gamma[c + 0] * (v.x - mu) * rsqrtf(var + EPSc) + beta[c + 0];
        }
        {
            float mu = stats[c + 1] * invN;
            float var = stats[Dd + c + 1] * invN - mu * mu;
            o.y = gamma[c + 1] * (v.y - mu) * rsqrtf(var + EPSc) + beta[c + 1];
        }
        {
            float mu = stats[c + 2] * invN;
            float var = stats[Dd + c + 2] * invN - mu * mu;
            o.z = gamma[c + 2] * (v.z - mu) * rsqrtf(var + EPSc) + beta[c + 2];
        }
        {
            float mu = stats[c + 3] * invN;
            float var = stats[Dd + c + 3] * invN - mu * mu;
            o.w = gamma[c + 3] * (v.w - mu) * rsqrtf(var + EPSc) + beta[c + 3];
        }
        ((float4*)out)[i] = o;
        if (xb) ((ushort4*)xb)[i] = make_ushort4(f2bf(o.x), f2bf(o.y),
                                                 f2bf(o.z), f2bf(o.w));
    }
}

// ---------------- launch ----------------
extern "C" void kernel_launch(void* const* d_in, const int* in_sizes, int n_in,
                              void* d_out, int out_size, void* d_ws, size_t ws_size,
                              hipStream_t stream) {
    const float* feat = (const float*)d_in[0];
    const int* src = (const int*)d_in[1];
    const int* dst = (const int*)d_in[2];
    const int* et = (const int*)d_in[3];
    float* out = (float*)d_out;

    // workspace (~70 MB)
    char* p = (char*)d_ws;
    u16* yb16 = (u16*)p;     p += (size_t)Nn * 512 * 2;                  // 51.2 MB
    u16* x16 = (u16*)p;      p += (size_t)Nn * 128 * 2;                  // 12.8 MB
    u16* Wt = (u16*)p;       p += (size_t)128 * 640 * 2;                 // 160 KB
    int* rowp = (int*)p;     p += ((((size_t)(Nn + 1) * 4) + 15) & ~15ull);
    int2* se = (int2*)p;     p += (size_t)Ee * 8;                        // 4.8 MB
    float* partials = (float*)p;  p += (size_t)GX * 256 * 4;             // 400 KB
    float* stats = (float*)p;     p += 2 * Dd * 4;
    int* bsum = (int*)p;          p += ((NB * 4 + 15) & ~15);
    int* boff = (int*)p;          p += ((NB * 4 + 15) & ~15);
    int* cursor = (int*)yb16;  // dead before agg_k writes yb16

    // ---- CSR once ----
    hipMemsetAsync(cursor, 0, (size_t)Nn * 4, stream);
    hist_k<<<(Ee + 255) / 256, 256, 0, stream>>>(dst, cursor);
    scanA_k<<<NB, 256, 0, stream>>>(cursor, rowp, bsum);
    scanB_k<<<1, 256, 0, stream>>>(bsum, boff);
    scanC_k<<<NB, 256, 0, stream>>>(boff, rowp);
    hipMemcpyAsync(cursor, rowp, (size_t)Nn * 4, hipMemcpyDeviceToDevice, stream);
    scatter_k<<<(Ee + 255) / 256, 256, 0, stream>>>(src, dst, et, cursor, se);
    conv_k<<<1024, 256, 0, stream>>>(feat, x16);

    for (int l = 0; l < 2; l++) {
        const float* V = (const float*)d_in[4 + 6 * l + 0];
        const float* comb = (const float*)d_in[4 + 6 * l + 1];
        const float* loop = (const float*)d_in[4 + 6 * l + 2];
        const float* bias = (const float*)d_in[4 + 6 * l + 3];
        const float* gamma = (const float*)d_in[4 + 6 * l + 4];
        const float* beta = (const float*)d_in[4 + 6 * l + 5];

        wprep_k<<<(128 * 640 + 255) / 256, 256, 0, stream>>>(V, loop, Wt);
        agg_k<<<(Nn + 3) / 4, 256, 0, stream>>>(x16, se, rowp, comb, yb16);
        hipMemsetAsync(stats, 0, 2 * Dd * sizeof(float), stream);
        gemm_mfma_k<<<GX, 256, 0, stream>>>(yb16, x16, Wt, bias, out, partials);
        red_k<<<8, 256, 0, stream>>>(partials, stats);
        norm_k<<<2048, 256, 0, stream>>>(out, stats, gamma, beta, out,
                                         (l == 0) ? x16 : nullptr);
    }
}

// Round 11
// 281.903 us; speedup vs baseline: 1.3125x; 1.0388x over previous
//
#include <hip/hip_runtime.h>
#include <hip/hip_bf16.h>

#define Nn 50000
#define Ee 600000
#define Dd 128
#define EPSc 1e-5f
#define GX 391   // gemm grid: ceil(50000/128)
#define NB 196   // scan tiles: ceil(50000/256)

typedef unsigned int u32;
typedef unsigned short u16;
typedef short s16x8 __attribute__((ext_vector_type(8)));
typedef float f32x4 __attribute__((ext_vector_type(4)));

__device__ inline float bf2f(u32 lo16) { return __uint_as_float(lo16 << 16); }
__device__ inline u16 f2bf(float f) {
    u32 b = __float_as_uint(f);
    return (u16)((b + 0x7fffu + ((b >> 16) & 1u)) >> 16);  // RTN-even
}
__device__ inline void gload16(const void* g, void* l) {
    __builtin_amdgcn_global_load_lds(
        (const __attribute__((address_space(1))) u32*)g,
        (__attribute__((address_space(3))) u32*)l, 16, 0, 0);
}

// ---------------- CSR build: histogram ----------------
__global__ __launch_bounds__(256) void hist_k(const int* __restrict__ dst,
                                              int* __restrict__ cnt) {
    int e = blockIdx.x * 256 + threadIdx.x;
    if (e < Ee) atomicAdd(&cnt[dst[e]], 1);
}

// ---------------- 3-pass scan ----------------
__global__ __launch_bounds__(256) void scanA_k(const int* __restrict__ cnt,
                                               int* __restrict__ rowp,
                                               int* __restrict__ bsum) {
    __shared__ int ws4[4];
    const int tid = threadIdx.x, lane = tid & 63, w = tid >> 6;
    const int i = blockIdx.x * 256 + tid;
    int v = (i < Nn) ? cnt[i] : 0;
    int incl = v;
#pragma unroll
    for (int off = 1; off < 64; off <<= 1) {
        int u = __shfl_up(incl, off, 64);
        if (lane >= off) incl += u;
    }
    if (lane == 63) ws4[w] = incl;
    __syncthreads();
    if (tid == 0) {
        int run = 0;
#pragma unroll
        for (int j = 0; j < 4; j++) { int s = ws4[j]; ws4[j] = run; run += s; }
    }
    __syncthreads();
    incl += ws4[w];
    if (i < Nn) rowp[i + 1] = incl;
    if (tid == 255) bsum[blockIdx.x] = incl;
}

__global__ __launch_bounds__(256) void scanB_k(const int* __restrict__ bsum,
                                               int* __restrict__ boff) {
    __shared__ int ws4[4];
    const int tid = threadIdx.x, lane = tid & 63, w = tid >> 6;
    int v = (tid < NB) ? bsum[tid] : 0;
    int incl = v;
#pragma unroll
    for (int off = 1; off < 64; off <<= 1) {
        int u = __shfl_up(incl, off, 64);
        if (lane >= off) incl += u;
    }
    if (lane == 63) ws4[w] = incl;
    __syncthreads();
    if (tid == 0) {
        int run = 0;
#pragma unroll
        for (int j = 0; j < 4; j++) { int s = ws4[j]; ws4[j] = run; run += s; }
    }
    __syncthreads();
    if (tid < NB) boff[tid] = incl + ws4[w] - v;  // exclusive
}

// adds block offsets; also seeds the scatter cursor (cursor[i] = rowp[i])
__global__ __launch_bounds__(256) void scanC_k(const int* __restrict__ boff,
                                               int* __restrict__ rowp,
                                               int* __restrict__ cursor) {
    const int i = blockIdx.x * 256 + threadIdx.x;
    if (i < Nn) {
        int v = rowp[i + 1] + boff[blockIdx.x];
        rowp[i + 1] = v;
        if (i + 1 < Nn) cursor[i + 1] = v;
    }
    if (i == 0) { rowp[0] = 0; cursor[0] = 0; }
}

__global__ __launch_bounds__(256) void scatter_k(const int* __restrict__ src,
                                                 const int* __restrict__ dst,
                                                 const int* __restrict__ et,
                                                 int* __restrict__ cursor,
                                                 int2* __restrict__ se) {
    int e = blockIdx.x * 256 + threadIdx.x;
    if (e < Ee) {
        int pos = atomicAdd(&cursor[dst[e]], 1);
        se[pos] = make_int2(src[e], et[e]);
    }
}

// ---------------- fp32 -> bf16 convert ----------------
__global__ __launch_bounds__(256) void conv_k(const float* __restrict__ in,
                                              u16* __restrict__ out) {
    const int total = Nn * 32;
    for (int i = blockIdx.x * 256 + threadIdx.x; i < total; i += gridDim.x * 256) {
        float4 v = ((const float4*)in)[i];
        ((ushort4*)out)[i] = make_ushort4(f2bf(v.x), f2bf(v.y), f2bf(v.z), f2bf(v.w));
    }
}

// ---------------- weight prep BOTH layers: Wt[l][c][k], k: V(512)|loop(128) --
__global__ __launch_bounds__(256) void wprep2_k(const float* __restrict__ V0,
                                                const float* __restrict__ loop0,
                                                const float* __restrict__ V1,
                                                const float* __restrict__ loop1,
                                                u16* __restrict__ Wt) {
    int i = blockIdx.x * 256 + threadIdx.x;  // 2*128*640
    if (i >= 2 * 128 * 640) return;
    int l = i / 81920, r = i - l * 81920;
    int c = r / 640, k = r - c * 640;
    const float* V = l ? V1 : V0;
    const float* lp = l ? loop1 : loop0;
    float v = (k < 512) ? V[(size_t)k * 128 + c] : lp[(size_t)(k - 512) * 128 + c];
    Wt[i] = f2bf(v);
}

// ---------------- aggregation: yb16[n,b,:] = sum_e comb[et,b]*x16[src] -------
// DUAL-CHAIN: each wave owns 2 consecutive nodes; per step, 4-deep chunks from
// BOTH chains -> 8 independent gathers in flight; tail edges zero-masked.
__global__ __launch_bounds__(256) void agg_k(const u16* __restrict__ x16,
                                             const int2* __restrict__ se,
                                             const int* __restrict__ rowp,
                                             const float* __restrict__ comb,
                                             u16* __restrict__ yb16) {
    const int wv = threadIdx.x >> 6;
    const int lane = threadIdx.x & 63;
    const int nA = blockIdx.x * 8 + wv * 2;   // grid = 6250 exactly covers 50000
    const int begA = rowp[nA], endA = rowp[nA + 1], endB = rowp[nA + 2];
    const int begB = endA;
    const int eLA = endA - 1, eLB = endB - 1;
    const u32 co = (u32)lane * 2u;

    float A0x = 0.f, A0y = 0.f, A1x = 0.f, A1y = 0.f;
    float A2x = 0.f, A2y = 0.f, A3x = 0.f, A3y = 0.f;
    float B0x = 0.f, B0y = 0.f, B1x = 0.f, B1y = 0.f;
    float B2x = 0.f, B2y = 0.f, B3x = 0.f, B3y = 0.f;

    const int degA = endA - begA, degB = endB - begB;
    const int nst = (max(degA, degB) + 3) >> 2;

    for (int s = 0; s < nst; s++) {
        const int eA = begA + s * 4, eB = begB + s * 4;
        const int mA = endA - eA, mB = endB - eB;
        int2 rc[8];
        u32 xv[8];
#pragma unroll
        for (int j = 0; j < 4; j++) {
            rc[j]     = se[(mA > 0) ? min(eA + j, eLA) : 0];
            rc[4 + j] = se[(mB > 0) ? min(eB + j, eLB) : 0];
        }
#pragma unroll
        for (int j = 0; j < 8; j++)
            xv[j] = *(const u32*)&x16[(size_t)(u32)rc[j].x * 128 + co];
#pragma unroll
        for (int j = 0; j < 4; j++) {
            if (j >= mA) xv[j] = 0;
            if (j >= mB) xv[4 + j] = 0;
        }
#pragma unroll
        for (int j = 0; j < 4; j++) {
            {
                const float4 c = ((const float4*)comb)[rc[j].y];
                const float fx = bf2f(xv[j] & 0xffffu);
                const float fy = bf2f(xv[j] >> 16);
                A0x += c.x * fx; A0y += c.x * fy;
                A1x += c.y * fx; A1y += c.y * fy;
                A2x += c.z * fx; A2y += c.z * fy;
                A3x += c.w * fx; A3y += c.w * fy;
            }
            {
                const float4 c = ((const float4*)comb)[rc[4 + j].y];
                const float fx = bf2f(xv[4 + j] & 0xffffu);
                const float fy = bf2f(xv[4 + j] >> 16);
                B0x += c.x * fx; B0y += c.x * fy;
                B1x += c.y * fx; B1y += c.y * fy;
                B2x += c.z * fx; B2y += c.z * fy;
                B3x += c.w * fx; B3y += c.w * fy;
            }
        }
    }
    u32* ypA = (u32*)(yb16 + (size_t)nA * 512);
    ypA[lane]       = (u32)f2bf(A0x) | ((u32)f2bf(A0y) << 16);
    ypA[64 + lane]  = (u32)f2bf(A1x) | ((u32)f2bf(A1y) << 16);
    ypA[128 + lane] = (u32)f2bf(A2x) | ((u32)f2bf(A2y) << 16);
    ypA[192 + lane] = (u32)f2bf(A3x) | ((u32)f2bf(A3y) << 16);
    u32* ypB = ypA + 256;
    ypB[lane]       = (u32)f2bf(B0x) | ((u32)f2bf(B0y) << 16);
    ypB[64 + lane]  = (u32)f2bf(B1x) | ((u32)f2bf(B1y) << 16);
    ypB[128 + lane] = (u32)f2bf(B2x) | ((u32)f2bf(B2y) << 16);
    ypB[192 + lane] = (u32)f2bf(B3x) | ((u32)f2bf(B3y) << 16);
}

// ---------------- MFMA GEMM: OUT = relu([yb16|x16] @ Wt^T + bias) ------------
__global__ __launch_bounds__(256) void gemm_mfma_k(const u16* __restrict__ yb16,
                                                   const u16* __restrict__ x16,
                                                   const u16* __restrict__ Wt,
                                                   const float* __restrict__ bias,
                                                   float* __restrict__ OUT,
                                                   float* __restrict__ partials) {
    __shared__ __align__(16) char As[8192];  // 128 rows x 64 B
    __shared__ __align__(16) char Bs[8192];  // 128 cols x 64 B
    const int tid = threadIdx.x;
    const int lane = tid & 63, wid = tid >> 6;
    const int wr = wid >> 1, wc = wid & 1;
    const int bm = blockIdx.x * 128;

    f32x4 acc[4][4] = {};

    const int r0 = wid * 32;
    const int lrow = lane >> 2;
    const int sphys = lane & 3;
    const int rowL0 = r0 + lrow, rowL1 = r0 + 16 + lrow;
    const int slog0 = (sphys ^ ((rowL0 >> 1) & 3)) * 8;
    const int slog1 = (sphys ^ ((rowL1 >> 1) & 3)) * 8;
    int ga0 = bm + rowL0; if (ga0 >= Nn) ga0 = Nn - 1;
    int ga1 = bm + rowL1; if (ga1 >= Nn) ga1 = Nn - 1;

    for (int k0 = 0; k0 < 640; k0 += 32) {
        __syncthreads();
        const u16 *as0, *as1;
        if (k0 < 512) {
            as0 = yb16 + (size_t)ga0 * 512 + k0 + slog0;
            as1 = yb16 + (size_t)ga1 * 512 + k0 + slog1;
        } else {
            as0 = x16 + (size_t)ga0 * 128 + (k0 - 512) + slog0;
            as1 = x16 + (size_t)ga1 * 128 + (k0 - 512) + slog1;
        }
        gload16(as0, &As[r0 * 64]);
        gload16(as1, &As[(r0 + 16) * 64]);
        gload16(Wt + (size_t)rowL0 * 640 + k0 + slog0, &Bs[r0 * 64]);
        gload16(Wt + (size_t)rowL1 * 640 + k0 + slog1, &Bs[(r0 + 16) * 64]);
        __syncthreads();
        s16x8 a[4], b[4];
#pragma unroll
        for (int m = 0; m < 4; m++) {
            int row = wr * 64 + m * 16 + (lane & 15);
            a[m] = *(const s16x8*)&As[row * 64 + (((lane >> 4) ^ ((row >> 1) & 3)) << 4)];
            int col = wc * 64 + m * 16 + (lane & 15);
            b[m] = *(const s16x8*)&Bs[col * 64 + (((lane >> 4) ^ ((col >> 1) & 3)) << 4)];
        }
#pragma unroll
        for (int m = 0; m < 4; m++)
#pragma unroll
            for (int n = 0; n < 4; n++)
                acc[m][n] = __builtin_amdgcn_mfma_f32_16x16x32_bf16(a[m], b[n],
                                                                    acc[m][n], 0, 0, 0);
    }
    float bv[4], cs[4] = {}, cq[4] = {};
#pragma unroll
    for (int n = 0; n < 4; n++) bv[n] = bias[wc * 64 + n * 16 + (lane & 15)];
#pragma unroll
    for (int m = 0; m < 4; m++) {
        const int rb = bm + wr * 64 + m * 16 + ((lane >> 4) << 2);
#pragma unroll
        for (int e = 0; e < 4; e++) {
            const int r = rb + e;
            if (r < Nn) {
                float* op = OUT + (size_t)r * 128 + wc * 64 + (lane & 15);
#pragma unroll
                for (int n = 0; n < 4; n++) {
                    float v = fmaxf(acc[m][n][e] + bv[n], 0.f);
                    op[n * 16] = v;
                    cs[n] += v;
                    cq[n] += v * v;
                }
            }
        }
    }
#pragma unroll
    for (int n = 0; n < 4; n++) {
        cs[n] += __shfl_xor(cs[n], 16);
        cs[n] += __shfl_xor(cs[n], 32);
        cq[n] += __shfl_xor(cq[n], 16);
        cq[n] += __shfl_xor(cq[n], 32);
    }
    __syncthreads();
    float* red = (float*)As;
    if (wr == 1 && lane < 16) {
#pragma unroll
        for (int n = 0; n < 4; n++) {
            const int col = wc * 64 + n * 16 + lane;
            red[col] = cs[n];
            red[128 + col] = cq[n];
        }
    }
    __syncthreads();
    if (wr == 0 && lane < 16) {
        float* pp = partials + (size_t)blockIdx.x * 256;
#pragma unroll
        for (int n = 0; n < 4; n++) {
            const int col = wc * 64 + n * 16 + lane;
            pp[col] = cs[n] + red[col];
            pp[128 + col] = cq[n] + red[128 + col];
        }
    }
}

// ---------------- partials reduce (1 block, no atomics, no memset) -----------
__global__ __launch_bounds__(256) void red_k(const float* __restrict__ partials,
                                             float* __restrict__ stats) {
    const int c = threadIdx.x;
    float s0 = 0.f, s1 = 0.f, s2 = 0.f, s3 = 0.f;
    int b = 0;
    for (; b + 4 <= GX; b += 4) {
        s0 += partials[(size_t)(b + 0) * 256 + c];
        s1 += partials[(size_t)(b + 1) * 256 + c];
        s2 += partials[(size_t)(b + 2) * 256 + c];
        s3 += partials[(size_t)(b + 3) * 256 + c];
    }
    for (; b < GX; b++) s0 += partials[(size_t)b * 256 + c];
    stats[c] = (s0 + s1) + (s2 + s3);
}

// ---------------- BN normalize; outp and/or xb may be null -------------------
__global__ __launch_bounds__(256) void norm_k(const float* __restrict__ h,
                                              const float* __restrict__ stats,
                                              const float* __restrict__ gamma,
                                              const float* __restrict__ beta,
                                              float* __restrict__ outp,
                                              u16* __restrict__ xb) {
    const float invN = 1.0f / (float)Nn;
    int total = Nn * 32;
    for (int i = blockIdx.x * blockDim.x + threadIdx.x; i < total;
         i += gridDim.x * blockDim.x) {
        int c = (i & 31) * 4;
        float4 v = ((const float4*)h)[i];
        float4 o;
        {
            float mu = stats[c + 0] * invN;
            float var = stats[Dd + c + 0] * invN - mu * mu;
            o.x = gamma[c + 0] * (v.x - mu) * rsqrtf(var + EPSc) + beta[c + 0];
        }
        {
            float mu = stats[c + 1] * invN;
            float var = stats[Dd + c + 1] * invN - mu * mu;
            o.y = gamma[c + 1] * (v.y - mu) * rsqrtf(var + EPSc) + beta[c + 1];
        }
        {
            float mu = stats[c + 2] * invN;
            float var = stats[Dd + c + 2] * invN - mu * mu;
            o.z = gamma[c + 2] * (v.z - mu) * rsqrtf(var + EPSc) + beta[c + 2];
        }
        {
            float mu = stats[c + 3] * invN;
            float var = stats[Dd + c + 3] * invN - mu * mu;
            o.w = gamma[c + 3] * (v.w - mu) * rsqrtf(var + EPSc) + beta[c + 3];
        }
        if (outp) ((float4*)outp)[i] = o;
        if (xb) ((ushort4*)xb)[i] = make_ushort4(f2bf(o.x), f2bf(o.y),
                                                 f2bf(o.z), f2bf(o.w));
    }
}

// ---------------- launch ----------------
extern "C" void kernel_launch(void* const* d_in, const int* in_sizes, int n_in,
                              void* d_out, int out_size, void* d_ws, size_t ws_size,
                              hipStream_t stream) {
    const float* feat = (const float*)d_in[0];
    const int* src = (const int*)d_in[1];
    const int* dst = (const int*)d_in[2];
    const int* et = (const int*)d_in[3];
    float* out = (float*)d_out;

    // workspace (~70 MB)
    char* p = (char*)d_ws;
    u16* yb16 = (u16*)p;     p += (size_t)Nn * 512 * 2;                  // 51.2 MB
    u16* x16 = (u16*)p;      p += (size_t)Nn * 128 * 2;                  // 12.8 MB
    u16* Wt = (u16*)p;       p += (size_t)2 * 128 * 640 * 2;             // 320 KB
    int* rowp = (int*)p;     p += ((((size_t)(Nn + 1) * 4) + 15) & ~15ull);
    int2* se = (int2*)p;     p += (size_t)Ee * 8;                        // 4.8 MB
    float* partials = (float*)p;  p += (size_t)GX * 256 * 4;             // 400 KB
    float* stats = (float*)p;     p += 2 * Dd * 4;
    int* bsum = (int*)p;          p += ((NB * 4 + 15) & ~15);
    int* boff = (int*)p;          p += ((NB * 4 + 15) & ~15);
    int* cursor = (int*)yb16;  // dead before agg_k writes yb16

    // ---- CSR + weights + x16, once ----
    hipMemsetAsync(cursor, 0, (size_t)Nn * 4, stream);
    hist_k<<<(Ee + 255) / 256, 256, 0, stream>>>(dst, cursor);
    scanA_k<<<NB, 256, 0, stream>>>(cursor, rowp, bsum);
    scanB_k<<<1, 256, 0, stream>>>(bsum, boff);
    scanC_k<<<NB, 256, 0, stream>>>(boff, rowp, cursor);
    scatter_k<<<(Ee + 255) / 256, 256, 0, stream>>>(src, dst, et, cursor, se);
    conv_k<<<1024, 256, 0, stream>>>(feat, x16);
    wprep2_k<<<(2 * 128 * 640 + 255) / 256, 256, 0, stream>>>(
        (const float*)d_in[4], (const float*)d_in[6],
        (const float*)d_in[10], (const float*)d_in[12], Wt);

    for (int l = 0; l < 2; l++) {
        const float* comb = (const float*)d_in[4 + 6 * l + 1];
        const float* bias = (const float*)d_in[4 + 6 * l + 3];
        const float* gamma = (const float*)d_in[4 + 6 * l + 4];
        const float* beta = (const float*)d_in[4 + 6 * l + 5];

        agg_k<<<Nn / 8, 256, 0, stream>>>(x16, se, rowp, comb, yb16);
        gemm_mfma_k<<<GX, 256, 0, stream>>>(yb16, x16, Wt + (size_t)l * 81920,
                                            bias, out, partials);
        red_k<<<1, 256, 0, stream>>>(partials, stats);
        norm_k<<<2048, 256, 0, stream>>>(out, stats, gamma, beta,
                                         (l == 0) ? nullptr : out,
                                         (l == 0) ? x16 : nullptr);
    }
}

// Round 12
// 267.590 us; speedup vs baseline: 1.3827x; 1.0535x over previous
//
#include <hip/hip_runtime.h>
#include <hip/hip_bf16.h>

#define Nn 50000
#define Ee 600000
#define Dd 128
#define EPSc 1e-5f
#define GX 391   // gemm grid: ceil(50000/128)
#define NB 196   // scan tiles: ceil(50000/256)

typedef unsigned int u32;
typedef unsigned short u16;
typedef short s16x8 __attribute__((ext_vector_type(8)));
typedef float f32x4 __attribute__((ext_vector_type(4)));

__device__ inline float bf2f(u32 lo16) { return __uint_as_float(lo16 << 16); }
__device__ inline u16 f2bf(float f) {
    u32 b = __float_as_uint(f);
    return (u16)((b + 0x7fffu + ((b >> 16) & 1u)) >> 16);  // RTN-even
}
__device__ inline void gload16(const void* g, void* l) {
    __builtin_amdgcn_global_load_lds(
        (const __attribute__((address_space(1))) u32*)g,
        (__attribute__((address_space(3))) u32*)l, 16, 0, 0);
}

// ---------------- CSR build: histogram ----------------
__global__ __launch_bounds__(256) void hist_k(const int* __restrict__ dst,
                                              int* __restrict__ cnt) {
    int e = blockIdx.x * 256 + threadIdx.x;
    if (e < Ee) atomicAdd(&cnt[dst[e]], 1);
}

// ---------------- 3-pass scan ----------------
__global__ __launch_bounds__(256) void scanA_k(const int* __restrict__ cnt,
                                               int* __restrict__ rowp,
                                               int* __restrict__ bsum) {
    __shared__ int ws4[4];
    const int tid = threadIdx.x, lane = tid & 63, w = tid >> 6;
    const int i = blockIdx.x * 256 + tid;
    int v = (i < Nn) ? cnt[i] : 0;
    int incl = v;
#pragma unroll
    for (int off = 1; off < 64; off <<= 1) {
        int u = __shfl_up(incl, off, 64);
        if (lane >= off) incl += u;
    }
    if (lane == 63) ws4[w] = incl;
    __syncthreads();
    if (tid == 0) {
        int run = 0;
#pragma unroll
        for (int j = 0; j < 4; j++) { int s = ws4[j]; ws4[j] = run; run += s; }
    }
    __syncthreads();
    incl += ws4[w];
    if (i < Nn) rowp[i + 1] = incl;
    if (tid == 255) bsum[blockIdx.x] = incl;
}

__global__ __launch_bounds__(256) void scanB_k(const int* __restrict__ bsum,
                                               int* __restrict__ boff) {
    __shared__ int ws4[4];
    const int tid = threadIdx.x, lane = tid & 63, w = tid >> 6;
    int v = (tid < NB) ? bsum[tid] : 0;
    int incl = v;
#pragma unroll
    for (int off = 1; off < 64; off <<= 1) {
        int u = __shfl_up(incl, off, 64);
        if (lane >= off) incl += u;
    }
    if (lane == 63) ws4[w] = incl;
    __syncthreads();
    if (tid == 0) {
        int run = 0;
#pragma unroll
        for (int j = 0; j < 4; j++) { int s = ws4[j]; ws4[j] = run; run += s; }
    }
    __syncthreads();
    if (tid < NB) boff[tid] = incl + ws4[w] - v;  // exclusive
}

// adds block offsets; also seeds the scatter cursor (cursor[i] = rowp[i])
__global__ __launch_bounds__(256) void scanC_k(const int* __restrict__ boff,
                                               int* __restrict__ rowp,
                                               int* __restrict__ cursor) {
    const int i = blockIdx.x * 256 + threadIdx.x;
    if (i < Nn) {
        int v = rowp[i + 1] + boff[blockIdx.x];
        rowp[i + 1] = v;
        if (i + 1 < Nn) cursor[i + 1] = v;
    }
    if (i == 0) { rowp[0] = 0; cursor[0] = 0; }
}

__global__ __launch_bounds__(256) void scatter_k(const int* __restrict__ src,
                                                 const int* __restrict__ dst,
                                                 const int* __restrict__ et,
                                                 int* __restrict__ cursor,
                                                 int2* __restrict__ se) {
    int e = blockIdx.x * 256 + threadIdx.x;
    if (e < Ee) {
        int pos = atomicAdd(&cursor[dst[e]], 1);
        se[pos] = make_int2(src[e], et[e]);
    }
}

// ---------------- fp32 -> bf16 convert ----------------
__global__ __launch_bounds__(256) void conv_k(const float* __restrict__ in,
                                              u16* __restrict__ out) {
    const int total = Nn * 32;
    for (int i = blockIdx.x * 256 + threadIdx.x; i < total; i += gridDim.x * 256) {
        float4 v = ((const float4*)in)[i];
        ((ushort4*)out)[i] = make_ushort4(f2bf(v.x), f2bf(v.y), f2bf(v.z), f2bf(v.w));
    }
}

// ---------------- weight prep BOTH layers: Wt[l][c][k], k: V(512)|loop(128) --
__global__ __launch_bounds__(256) void wprep2_k(const float* __restrict__ V0,
                                                const float* __restrict__ loop0,
                                                const float* __restrict__ V1,
                                                const float* __restrict__ loop1,
                                                u16* __restrict__ Wt) {
    int i = blockIdx.x * 256 + threadIdx.x;  // 2*128*640
    if (i >= 2 * 128 * 640) return;
    int l = i / 81920, r = i - l * 81920;
    int c = r / 640, k = r - c * 640;
    const float* V = l ? V1 : V0;
    const float* lp = l ? loop1 : loop0;
    float v = (k < 512) ? V[(size_t)k * 128 + c] : lp[(size_t)(k - 512) * 128 + c];
    Wt[i] = f2bf(v);
}

// ---------------- aggregation: yb16[n,b,:] = sum_e comb[et,b]*x16[src] -------
// R6-proven structure: 1 node/wave, 4-deep MLP chunks, tail zero-masked.
// Bound by per-CU gather line rate (~14 cyc/line); depth-4 minimizes slot waste.
__global__ __launch_bounds__(256) void agg_k(const u16* __restrict__ x16,
                                             const int2* __restrict__ se,
                                             const int* __restrict__ rowp,
                                             const float* __restrict__ comb,
                                             u16* __restrict__ yb16) {
    const int node = blockIdx.x * 4 + (threadIdx.x >> 6);
    const int lane = threadIdx.x & 63;
    const int beg = rowp[node], end = rowp[node + 1];
    float a0x = 0.f, a0y = 0.f, a1x = 0.f, a1y = 0.f;
    float a2x = 0.f, a2y = 0.f, a3x = 0.f, a3y = 0.f;
    const int eL = end - 1;
    const int co = lane * 2;

    for (int e0 = beg; e0 < end; e0 += 4) {
        const int m = end - e0;
        const int2 rc0 = se[e0];
        const int2 rc1 = se[min(e0 + 1, eL)];
        const int2 rc2 = se[min(e0 + 2, eL)];
        const int2 rc3 = se[min(e0 + 3, eL)];
        u32 x0 = *(const u32*)&x16[(size_t)rc0.x * 128 + co];
        u32 x1 = *(const u32*)&x16[(size_t)rc1.x * 128 + co];
        u32 x2 = *(const u32*)&x16[(size_t)rc2.x * 128 + co];
        u32 x3 = *(const u32*)&x16[(size_t)rc3.x * 128 + co];
        if (m < 4) x3 = 0;
        if (m < 3) x2 = 0;
        if (m < 2) x1 = 0;
        const float4 c0 = ((const float4*)comb)[rc0.y];
        const float4 c1 = ((const float4*)comb)[rc1.y];
        const float4 c2 = ((const float4*)comb)[rc2.y];
        const float4 c3 = ((const float4*)comb)[rc3.y];
#define ACC1(c, xv)                                        \
        {                                                  \
            const float fx = bf2f((xv) & 0xffffu);         \
            const float fy = bf2f((xv) >> 16);             \
            a0x += c.x * fx; a0y += c.x * fy;              \
            a1x += c.y * fx; a1y += c.y * fy;              \
            a2x += c.z * fx; a2y += c.z * fy;              \
            a3x += c.w * fx; a3y += c.w * fy;              \
        }
        ACC1(c0, x0)
        ACC1(c1, x1)
        ACC1(c2, x2)
        ACC1(c3, x3)
#undef ACC1
    }
    u32* yp = (u32*)(yb16 + (size_t)node * 512);
    yp[lane]       = (u32)f2bf(a0x) | ((u32)f2bf(a0y) << 16);
    yp[64 + lane]  = (u32)f2bf(a1x) | ((u32)f2bf(a1y) << 16);
    yp[128 + lane] = (u32)f2bf(a2x) | ((u32)f2bf(a2y) << 16);
    yp[192 + lane] = (u32)f2bf(a3x) | ((u32)f2bf(a3y) << 16);
}

// ---------------- MFMA GEMM: h16 = relu([yb16|x16] @ Wt^T + bias) (bf16 out) -
// BM=128,BN=128,BK=32, 4 waves (2x2 of 64x64), single 16KB LDS buffer.
// Epilogue: bf16 h store (halves write bytes); per-block column partials
// (sum|sumsq from fp32 regs) -> plain stores, NO atomics.
__global__ __launch_bounds__(256) void gemm_mfma_k(const u16* __restrict__ yb16,
                                                   const u16* __restrict__ x16,
                                                   const u16* __restrict__ Wt,
                                                   const float* __restrict__ bias,
                                                   u16* __restrict__ H16,
                                                   float* __restrict__ partials) {
    __shared__ __align__(16) char As[8192];  // 128 rows x 64 B
    __shared__ __align__(16) char Bs[8192];  // 128 cols x 64 B
    const int tid = threadIdx.x;
    const int lane = tid & 63, wid = tid >> 6;
    const int wr = wid >> 1, wc = wid & 1;
    const int bm = blockIdx.x * 128;

    f32x4 acc[4][4] = {};

    const int r0 = wid * 32;
    const int lrow = lane >> 2;
    const int sphys = lane & 3;
    const int rowL0 = r0 + lrow, rowL1 = r0 + 16 + lrow;
    const int slog0 = (sphys ^ ((rowL0 >> 1) & 3)) * 8;
    const int slog1 = (sphys ^ ((rowL1 >> 1) & 3)) * 8;
    int ga0 = bm + rowL0; if (ga0 >= Nn) ga0 = Nn - 1;
    int ga1 = bm + rowL1; if (ga1 >= Nn) ga1 = Nn - 1;

    for (int k0 = 0; k0 < 640; k0 += 32) {
        __syncthreads();
        const u16 *as0, *as1;
        if (k0 < 512) {
            as0 = yb16 + (size_t)ga0 * 512 + k0 + slog0;
            as1 = yb16 + (size_t)ga1 * 512 + k0 + slog1;
        } else {
            as0 = x16 + (size_t)ga0 * 128 + (k0 - 512) + slog0;
            as1 = x16 + (size_t)ga1 * 128 + (k0 - 512) + slog1;
        }
        gload16(as0, &As[r0 * 64]);
        gload16(as1, &As[(r0 + 16) * 64]);
        gload16(Wt + (size_t)rowL0 * 640 + k0 + slog0, &Bs[r0 * 64]);
        gload16(Wt + (size_t)rowL1 * 640 + k0 + slog1, &Bs[(r0 + 16) * 64]);
        __syncthreads();
        s16x8 a[4], b[4];
#pragma unroll
        for (int m = 0; m < 4; m++) {
            int row = wr * 64 + m * 16 + (lane & 15);
            a[m] = *(const s16x8*)&As[row * 64 + (((lane >> 4) ^ ((row >> 1) & 3)) << 4)];
            int col = wc * 64 + m * 16 + (lane & 15);
            b[m] = *(const s16x8*)&Bs[col * 64 + (((lane >> 4) ^ ((col >> 1) & 3)) << 4)];
        }
#pragma unroll
        for (int m = 0; m < 4; m++)
#pragma unroll
            for (int n = 0; n < 4; n++)
                acc[m][n] = __builtin_amdgcn_mfma_f32_16x16x32_bf16(a[m], b[n],
                                                                    acc[m][n], 0, 0, 0);
    }
    float bv[4], cs[4] = {}, cq[4] = {};
#pragma unroll
    for (int n = 0; n < 4; n++) bv[n] = bias[wc * 64 + n * 16 + (lane & 15)];
#pragma unroll
    for (int m = 0; m < 4; m++) {
        const int rb = bm + wr * 64 + m * 16 + ((lane >> 4) << 2);
#pragma unroll
        for (int e = 0; e < 4; e++) {
            const int r = rb + e;
            if (r < Nn) {
                u16* hp = H16 + (size_t)r * 128 + wc * 64 + (lane & 15);
#pragma unroll
                for (int n = 0; n < 4; n++) {
                    float v = fmaxf(acc[m][n][e] + bv[n], 0.f);
                    hp[n * 16] = f2bf(v);
                    cs[n] += v;
                    cq[n] += v * v;
                }
            }
        }
    }
#pragma unroll
    for (int n = 0; n < 4; n++) {
        cs[n] += __shfl_xor(cs[n], 16);
        cs[n] += __shfl_xor(cs[n], 32);
        cq[n] += __shfl_xor(cq[n], 16);
        cq[n] += __shfl_xor(cq[n], 32);
    }
    __syncthreads();
    float* red = (float*)As;
    if (wr == 1 && lane < 16) {
#pragma unroll
        for (int n = 0; n < 4; n++) {
            const int col = wc * 64 + n * 16 + lane;
            red[col] = cs[n];
            red[128 + col] = cq[n];
        }
    }
    __syncthreads();
    if (wr == 0 && lane < 16) {
        float* pp = partials + (size_t)blockIdx.x * 256;
#pragma unroll
        for (int n = 0; n < 4; n++) {
            const int col = wc * 64 + n * 16 + lane;
            pp[col] = cs[n] + red[col];
            pp[128 + col] = cq[n] + red[128 + col];
        }
    }
}

// ---------------- partials reduce (1 block, no atomics, no memset) -----------
__global__ __launch_bounds__(256) void red_k(const float* __restrict__ partials,
                                             float* __restrict__ stats) {
    const int c = threadIdx.x;
    float s0 = 0.f, s1 = 0.f, s2 = 0.f, s3 = 0.f;
    int b = 0;
    for (; b + 4 <= GX; b += 4) {
        s0 += partials[(size_t)(b + 0) * 256 + c];
        s1 += partials[(size_t)(b + 1) * 256 + c];
        s2 += partials[(size_t)(b + 2) * 256 + c];
        s3 += partials[(size_t)(b + 3) * 256 + c];
    }
    for (; b < GX; b++) s0 += partials[(size_t)b * 256 + c];
    stats[c] = (s0 + s1) + (s2 + s3);
}

// ---------------- BN normalize from bf16 h; outp and/or xb may be null -------
__global__ __launch_bounds__(256) void norm_k(const u16* __restrict__ h16,
                                              const float* __restrict__ stats,
                                              const float* __restrict__ gamma,
                                              const float* __restrict__ beta,
                                              float* __restrict__ outp,
                                              u16* __restrict__ xb) {
    const float invN = 1.0f / (float)Nn;
    int total = Nn * 32;
    for (int i = blockIdx.x * blockDim.x + threadIdx.x; i < total;
         i += gridDim.x * blockDim.x) {
        int c = (i & 31) * 4;
        ushort4 hv = ((const ushort4*)h16)[i];
        float4 o;
        {
            float mu = stats[c + 0] * invN;
            float var = stats[Dd + c + 0] * invN - mu * mu;
            o.x = gamma[c + 0] * (bf2f(hv.x) - mu) * rsqrtf(var + EPSc) + beta[c + 0];
        }
        {
            float mu = stats[c + 1] * invN;
            float var = stats[Dd + c + 1] * invN - mu * mu;
            o.y = gamma[c + 1] * (bf2f(hv.y) - mu) * rsqrtf(var + EPSc) + beta[c + 1];
        }
        {
            float mu = stats[c + 2] * invN;
            float var = stats[Dd + c + 2] * invN - mu * mu;
            o.z = gamma[c + 2] * (bf2f(hv.z) - mu) * rsqrtf(var + EPSc) + beta[c + 2];
        }
        {
            float mu = stats[c + 3] * invN;
            float var = stats[Dd + c + 3] * invN - mu * mu;
            o.w = gamma[c + 3] * (bf2f(hv.w) - mu) * rsqrtf(var + EPSc) + beta[c + 3];
        }
        if (outp) ((float4*)outp)[i] = o;
        if (xb) ((ushort4*)xb)[i] = make_ushort4(f2bf(o.x), f2bf(o.y),
                                                 f2bf(o.z), f2bf(o.w));
    }
}

// ---------------- launch ----------------
extern "C" void kernel_launch(void* const* d_in, const int* in_sizes, int n_in,
                              void* d_out, int out_size, void* d_ws, size_t ws_size,
                              hipStream_t stream) {
    const float* feat = (const float*)d_in[0];
    const int* src = (const int*)d_in[1];
    const int* dst = (const int*)d_in[2];
    const int* et = (const int*)d_in[3];
    float* out = (float*)d_out;

    // workspace (~83 MB)
    char* p = (char*)d_ws;
    u16* yb16 = (u16*)p;     p += (size_t)Nn * 512 * 2;                  // 51.2 MB
    u16* x16 = (u16*)p;      p += (size_t)Nn * 128 * 2;                  // 12.8 MB
    u16* h16 = (u16*)p;      p += (size_t)Nn * 128 * 2;                  // 12.8 MB
    u16* Wt = (u16*)p;       p += (size_t)2 * 128 * 640 * 2;             // 320 KB
    int* rowp = (int*)p;     p += ((((size_t)(Nn + 1) * 4) + 15) & ~15ull);
    int2* se = (int2*)p;     p += (size_t)Ee * 8;                        // 4.8 MB
    float* partials = (float*)p;  p += (size_t)GX * 256 * 4;             // 400 KB
    float* stats = (float*)p;     p += 2 * Dd * 4;
    int* bsum = (int*)p;          p += ((NB * 4 + 15) & ~15);
    int* boff = (int*)p;          p += ((NB * 4 + 15) & ~15);
    int* cursor = (int*)yb16;  // dead before agg_k writes yb16

    // ---- CSR + weights + x16, once ----
    hipMemsetAsync(cursor, 0, (size_t)Nn * 4, stream);
    hist_k<<<(Ee + 255) / 256, 256, 0, stream>>>(dst, cursor);
    scanA_k<<<NB, 256, 0, stream>>>(cursor, rowp, bsum);
    scanB_k<<<1, 256, 0, stream>>>(bsum, boff);
    scanC_k<<<NB, 256, 0, stream>>>(boff, rowp, cursor);
    scatter_k<<<(Ee + 255) / 256, 256, 0, stream>>>(src, dst, et, cursor, se);
    conv_k<<<1024, 256, 0, stream>>>(feat, x16);
    wprep2_k<<<(2 * 128 * 640 + 255) / 256, 256, 0, stream>>>(
        (const float*)d_in[4], (const float*)d_in[6],
        (const float*)d_in[10], (const float*)d_in[12], Wt);

    for (int l = 0; l < 2; l++) {
        const float* comb = (const float*)d_in[4 + 6 * l + 1];
        const float* bias = (const float*)d_in[4 + 6 * l + 3];
        const float* gamma = (const float*)d_in[4 + 6 * l + 4];
        const float* beta = (const float*)d_in[4 + 6 * l + 5];

        agg_k<<<Nn / 4, 256, 0, stream>>>(x16, se, rowp, comb, yb16);
        gemm_mfma_k<<<GX, 256, 0, stream>>>(yb16, x16, Wt + (size_t)l * 81920,
                                            bias, h16, partials);
        red_k<<<1, 256, 0, stream>>>(partials, stats);
        norm_k<<<2048, 256, 0, stream>>>(h16, stats, gamma, beta,
                                         (l == 0) ? nullptr : out,
                                         (l == 0) ? x16 : nullptr);
    }
}